// Round 2
// baseline (4975.595 us; speedup 1.0000x reference)
//
#include <hip/hip_runtime.h>
#include <hip/hip_fp16.h>

// Entropic OT (Sinkhorn), B=64, n=m=1024, d=64, eps=0.1, 50 iters.
// q[b,i,j] = <s_i,t_j> (unit rows) stored once as fp16 (128 MiB, LLC-resident).
// cost = 2-2q exactly (dist**2 undoes sqrt). All math in log2 domain:
// log2 K = CK*q - CK, CK = 20*log2(e). Direct exp2-sum LSE (args stay in
// [-80,+15] log2-units -> no max-subtract needed in fp32).
//
// Per iteration: row_pass (wave/row LSE) then col_pass (thread-owns-8-columns,
// 32-way row-split, atomicAdd partial colsums). The NEXT row_pass converts raw
// colsums to potentials (-10 - log2 S) and zeroes the ping-pong buffer.
// The 50th col_pass also accumulates cost-weighted sums; final answer is
// sum_j ccol_j / pcol_j / 65536 (since 2^lv_j = 2^-10 / S_j, mean /64).

#define BATCH 64
#define NPT   1024
#define DIM   64
#define CKF   28.853900817779268f   // 20 * log2(e)
#define NEG10 (-10.0f)              // log2-domain log_a = -log2(1024)
#define RS    32                    // col_pass row-slices per batch

#if __has_builtin(__builtin_amdgcn_exp2f)
#define EXP2F(x) __builtin_amdgcn_exp2f(x)
#else
#define EXP2F(x) exp2f(x)
#endif

__device__ __forceinline__ float2 h2tof2(unsigned int u) {
  return __half22float2(__builtin_bit_cast(__half2, u));
}
__device__ __forceinline__ void dec8(uint4 pk, float* f) {
  float2 t;
  t = h2tof2(pk.x); f[0] = t.x; f[1] = t.y;
  t = h2tof2(pk.y); f[2] = t.x; f[3] = t.y;
  t = h2tof2(pk.z); f[4] = t.x; f[5] = t.y;
  t = h2tof2(pk.w); f[6] = t.x; f[7] = t.y;
}

// ---------------------------------------------------------------------------
// build_q: per-batch GEMM dot[i,j] = <s_i/|s_i|, t_j/|t_j|>, fp16 out.
// 64x64 tile, 256 threads, 4x4 microkernel, fp32 VALU.
// ---------------------------------------------------------------------------
__global__ __launch_bounds__(256) void build_q(
    const float* __restrict__ src, const float* __restrict__ tgt,
    __half* __restrict__ q)
{
  __shared__ float sA[DIM][68];
  __shared__ float sB[DIM][68];

  const int b    = blockIdx.x >> 8;
  const int tile = blockIdx.x & 255;
  const int i0 = (tile >> 4) << 6;
  const int j0 = (tile & 15) << 6;
  const int tid = threadIdx.x;
  const int r = tid >> 2;
  const int c = tid & 3;

  {
    const float4* p4 = (const float4*)(src + ((size_t)b * NPT + (i0 + r)) * DIM + c * 16);
    float4 a0 = p4[0], a1 = p4[1], a2 = p4[2], a3 = p4[3];
    float v[16] = {a0.x,a0.y,a0.z,a0.w, a1.x,a1.y,a1.z,a1.w,
                   a2.x,a2.y,a2.z,a2.w, a3.x,a3.y,a3.z,a3.w};
    float ss = 0.f;
    #pragma unroll
    for (int k = 0; k < 16; ++k) ss = fmaf(v[k], v[k], ss);
    ss += __shfl_xor(ss, 1);
    ss += __shfl_xor(ss, 2);
    const float sc = 1.0f / fmaxf(sqrtf(ss), 1e-12f);
    #pragma unroll
    for (int k = 0; k < 16; ++k) sA[c * 16 + k][r] = v[k] * sc;
  }
  {
    const float4* p4 = (const float4*)(tgt + ((size_t)b * NPT + (j0 + r)) * DIM + c * 16);
    float4 a0 = p4[0], a1 = p4[1], a2 = p4[2], a3 = p4[3];
    float v[16] = {a0.x,a0.y,a0.z,a0.w, a1.x,a1.y,a1.z,a1.w,
                   a2.x,a2.y,a2.z,a2.w, a3.x,a3.y,a3.z,a3.w};
    float ss = 0.f;
    #pragma unroll
    for (int k = 0; k < 16; ++k) ss = fmaf(v[k], v[k], ss);
    ss += __shfl_xor(ss, 1);
    ss += __shfl_xor(ss, 2);
    const float sc = 1.0f / fmaxf(sqrtf(ss), 1e-12f);
    #pragma unroll
    for (int k = 0; k < 16; ++k) sB[c * 16 + k][r] = v[k] * sc;
  }
  __syncthreads();

  const int mi = (tid >> 4) << 2;
  const int mj = (tid & 15) << 2;
  float acc[4][4] = {};
  #pragma unroll 16
  for (int d = 0; d < DIM; ++d) {
    const float4 a = *(const float4*)&sA[d][mi];
    const float4 t = *(const float4*)&sB[d][mj];
    const float av[4] = {a.x, a.y, a.z, a.w};
    const float tv[4] = {t.x, t.y, t.z, t.w};
    #pragma unroll
    for (int ii = 0; ii < 4; ++ii)
      #pragma unroll
      for (int jj = 0; jj < 4; ++jj)
        acc[ii][jj] = fmaf(av[ii], tv[jj], acc[ii][jj]);
  }

  #pragma unroll
  for (int ii = 0; ii < 4; ++ii) {
    __half2 h0 = __floats2half2_rn(acc[ii][0], acc[ii][1]);
    __half2 h1 = __floats2half2_rn(acc[ii][2], acc[ii][3]);
    uint2 pk = { __builtin_bit_cast(unsigned int, h0),
                 __builtin_bit_cast(unsigned int, h1) };
    *(uint2*)(q + (size_t)b * NPT * NPT
                + (size_t)(i0 + mi + ii) * NPT + (j0 + mj)) = pk;
  }
}

// ---------------------------------------------------------------------------
// row_pass: lu[b,i] = -10 - log2( sum_j 2^(CK*q + w_j) ),
//   w_j = lv_j - CK, where lv_j = 0 (FIRST) or -10 - log2(pcol_r[b,j]).
// Also zeroes pcol_z (the buffer the NEXT col_pass accumulates into).
// One wave per row, lane covers 16 consecutive j, 16 rows per wave.
// ---------------------------------------------------------------------------
template<bool FIRST>
__global__ __launch_bounds__(256, 4) void row_pass(
    const __half* __restrict__ q, const float* __restrict__ pcol_r,
    float* __restrict__ pcol_z, float* __restrict__ lu)
{
  const int b    = blockIdx.x >> 4;
  const int rblk = blockIdx.x & 15;
  const int wave = threadIdx.x >> 6;
  const int lane = threadIdx.x & 63;

  float w[16];
  if (FIRST) {
    #pragma unroll
    for (int k = 0; k < 16; ++k) w[k] = -CKF;
  } else {
    const float4* wp = (const float4*)(pcol_r + ((size_t)b << 10) + lane * 16);
    const float4 s0 = wp[0], s1 = wp[1], s2 = wp[2], s3 = wp[3];
    const float sv[16] = {s0.x,s0.y,s0.z,s0.w, s1.x,s1.y,s1.z,s1.w,
                          s2.x,s2.y,s2.z,s2.w, s3.x,s3.y,s3.z,s3.w};
    #pragma unroll
    for (int k = 0; k < 16; ++k) w[k] = (NEG10 - CKF) - log2f(sv[k]);
    // zero ping-pong buffer for the NEXT col_pass (its readers all finished
    // in previous kernels; its writers start after this kernel ends)
    if (threadIdx.x < 64)
      pcol_z[((size_t)b << 10) + (rblk << 6) + threadIdx.x] = 0.f;
  }

  const __half* qb = q + ((size_t)b << 20);
  #pragma unroll 2
  for (int rr = 0; rr < 16; ++rr) {
    const int i = (rblk << 6) + (rr << 2) + wave;
    const uint4* rp = (const uint4*)(qb + ((size_t)i << 10) + lane * 16);
    const uint4 pa = rp[0];
    const uint4 pb = rp[1];
    float f[16];
    dec8(pa, f);
    dec8(pb, f + 8);

    float a0 = 0.f, a1 = 0.f;
    #pragma unroll
    for (int e = 0; e < 16; e += 2) {
      a0 += EXP2F(fmaf(f[e],     CKF, w[e]));
      a1 += EXP2F(fmaf(f[e + 1], CKF, w[e + 1]));
    }
    float s = a0 + a1;
    #pragma unroll
    for (int m = 1; m <= 32; m <<= 1) s += __shfl_xor(s, m);
    if (lane == 0) lu[((size_t)b << 10) + i] = NEG10 - log2f(s);
  }
}

// ---------------------------------------------------------------------------
// col_pass: raw colsums pcol[b,j] += sum_{i in slice} 2^(CK*q + lu_i - CK).
// Thread owns 8 consecutive columns (uint4 load, 16B/lane, coalesced).
// 32-way row split -> 2048 blocks of 128 thr (4 waves/SIMD).
// FINAL also accumulates ccol[b,j] += sum p * (2-2q).
// ---------------------------------------------------------------------------
template<bool FINAL>
__global__ __launch_bounds__(128, 4) void col_pass(
    const __half* __restrict__ q, const float* __restrict__ lu,
    float* __restrict__ pcol, float* __restrict__ ccol)
{
  const int b  = blockIdx.x >> 5;
  const int rs = blockIdx.x & 31;
  const int j8 = threadIdx.x << 3;

  const __half* qb = q + ((size_t)b << 20) + ((size_t)(rs << 5) << 10) + j8;
  const float*  ub = lu + ((size_t)b << 10) + (rs << 5);

  float acc[8]  = {};
  float cacc[8] = {};
  #pragma unroll 4
  for (int r = 0; r < 32; ++r) {
    const uint4 pk = *(const uint4*)(qb + ((size_t)r << 10));
    const float wr = ub[r] - CKF;
    float f[8];
    dec8(pk, f);
    #pragma unroll
    for (int e = 0; e < 8; ++e) {
      const float p = EXP2F(fmaf(f[e], CKF, wr));
      acc[e] += p;
      if (FINAL) cacc[e] = fmaf(p, fmaf(f[e], -2.0f, 2.0f), cacc[e]);
    }
  }

  float* pc = pcol + ((size_t)b << 10) + j8;
  #pragma unroll
  for (int e = 0; e < 8; ++e) atomicAdd(&pc[e], acc[e]);
  if (FINAL) {
    float* cc = ccol + ((size_t)b << 10) + j8;
    #pragma unroll
    for (int e = 0; e < 8; ++e) atomicAdd(&cc[e], cacc[e]);
  }
}

// ---------------------------------------------------------------------------
// final: mean_b sum_j ccol/pcol * 2^-10 / 64  ( = /65536 )
// ---------------------------------------------------------------------------
__global__ __launch_bounds__(256) void final_reduce(
    const float* __restrict__ pcol, const float* __restrict__ ccol,
    float* __restrict__ out)
{
  const int b = blockIdx.x;
  float s = 0.f;
  for (int j = threadIdx.x; j < NPT; j += 256) {
    const size_t k = ((size_t)b << 10) + j;
    s += ccol[k] / pcol[k];
  }
  #pragma unroll
  for (int m = 1; m <= 32; m <<= 1) s += __shfl_xor(s, m);
  __shared__ float ls[4];
  if ((threadIdx.x & 63) == 0) ls[threadIdx.x >> 6] = s;
  __syncthreads();
  if (threadIdx.x == 0)
    atomicAdd(out, (ls[0] + ls[1] + ls[2] + ls[3]) * (1.0f / 65536.0f));
}

// ---------------------------------------------------------------------------
extern "C" void kernel_launch(void* const* d_in, const int* in_sizes, int n_in,
                              void* d_out, int out_size, void* d_ws, size_t ws_size,
                              hipStream_t stream)
{
  (void)in_sizes; (void)n_in; (void)out_size; (void)ws_size;
  const float* src = (const float*)d_in[0];
  const float* tgt = (const float*)d_in[1];

  char* ws = (char*)d_ws;
  __half* q = (__half*)ws;                                    // 128 MiB
  const size_t QB = (size_t)BATCH * NPT * NPT * sizeof(__half);
  float* pcol0 = (float*)(ws + QB);                           // 256 KB
  float* pcol1 = pcol0 + BATCH * NPT;                         // 256 KB
  float* ccol  = pcol1 + BATCH * NPT;                         // 256 KB
  float* lu    = ccol  + BATCH * NPT;                         // 256 KB
  float* pp[2] = {pcol0, pcol1};

  // zero pcol0|pcol1|ccol (contiguous) and the output accumulator
  hipMemsetAsync(pcol0, 0, 3 * BATCH * NPT * sizeof(float), stream);
  hipMemsetAsync(d_out, 0, sizeof(float), stream);

  build_q<<<BATCH * 256, 256, 0, stream>>>(src, tgt, q);

  for (int t = 0; t < 50; ++t) {
    // row_pass(t): reads pcol[(t-1)&1] (t>0), zeroes pcol[t&1], writes lu
    if (t == 0)
      row_pass<true><<<BATCH * 16, 256, 0, stream>>>(q, nullptr, nullptr, lu);
    else
      row_pass<false><<<BATCH * 16, 256, 0, stream>>>(q, pp[(t - 1) & 1], pp[t & 1], lu);
    // col_pass(t): accumulates pcol[t&1]
    if (t == 49)
      col_pass<true><<<BATCH * RS, 128, 0, stream>>>(q, lu, pp[t & 1], ccol);
    else
      col_pass<false><<<BATCH * RS, 128, 0, stream>>>(q, lu, pp[t & 1], nullptr);
  }

  final_reduce<<<BATCH, 256, 0, stream>>>(pp[49 & 1], ccol, (float*)d_out);
}